// Round 14
// baseline (126.549 us; speedup 1.0000x reference)
//
#include <hip/hip_runtime.h>

typedef float f32x4 __attribute__((ext_vector_type(4)));
typedef __bf16 bf16x8 __attribute__((ext_vector_type(8)));

#define D_MODEL 1024
#define SEQ     2048
#define NB      2
#define NH      16
#define DK      64

__device__ __forceinline__ unsigned short f2bf(float f) {
    union { float f; unsigned int u; } un; un.f = f;
    unsigned int r = un.u + 0x7fffu + ((un.u >> 16) & 1u);
    return (unsigned short)(r >> 16);
}

__device__ __forceinline__ unsigned cvtpk(float lo, float hi) {
    unsigned r;
    asm("v_cvt_pk_bf16_f32 %0, %1, %2" : "=v"(r) : "v"(lo), "v"(hi));
    return r;
}

__device__ __forceinline__ void gload16(const void* g, void* l) {
    __builtin_amdgcn_global_load_lds((__attribute__((address_space(1))) void*)g,
                                     (__attribute__((address_space(3))) void*)l,
                                     16, 0, 0);
}

// ---------------------------------------------------------------------------
// fused fp32 -> bf16 casts for x and the 4 weights + RoPE cos/sin table
// ---------------------------------------------------------------------------
__global__ __launch_bounds__(256) void cast5(
    const float* __restrict__ x,  const float* __restrict__ wq,
    const float* __restrict__ wk, const float* __restrict__ wv,
    const float* __restrict__ wo,
    unsigned short* __restrict__ xb,  unsigned short* __restrict__ wqb,
    unsigned short* __restrict__ wkb, unsigned short* __restrict__ wvb,
    unsigned short* __restrict__ wob, float2* __restrict__ tab)
{
    if (blockIdx.y == 5) {  // RoPE table: [ss][p] -> (cos, sin), p = d/2 index
        int idx = blockIdx.x * 256 + threadIdx.x;
        if (idx < SEQ * 32) {
            int ss = idx >> 5, p = idx & 31;
            float freq = exp2f(-0.41524101186f * (float)p);  // 10000^(-p/32)
            float sn, cs;
            sincosf((float)ss * freq, &sn, &cs);
            tab[idx] = make_float2(cs, sn);
        }
        return;
    }
    const float* src; unsigned short* dst; int n8;
    switch (blockIdx.y) {
        case 0:  src = x;  dst = xb;  n8 = (NB*SEQ*D_MODEL)/8; break;
        case 1:  src = wq; dst = wqb; n8 = (D_MODEL*D_MODEL)/8; break;
        case 2:  src = wk; dst = wkb; n8 = (D_MODEL*D_MODEL)/8; break;
        case 3:  src = wv; dst = wvb; n8 = (D_MODEL*D_MODEL)/8; break;
        default: src = wo; dst = wob; n8 = (D_MODEL*D_MODEL)/8; break;
    }
    int stride = gridDim.x * blockDim.x;
    for (int i = blockIdx.x * blockDim.x + threadIdx.x; i < n8; i += stride) {
        const float4* p = (const float4*)src + (size_t)i * 2;
        float4 a = p[0], b = p[1];
        union { unsigned short h[8]; uint4 v; } u;
        u.h[0] = f2bf(a.x); u.h[1] = f2bf(a.y); u.h[2] = f2bf(a.z); u.h[3] = f2bf(a.w);
        u.h[4] = f2bf(b.x); u.h[5] = f2bf(b.y); u.h[6] = f2bf(b.z); u.h[7] = f2bf(b.w);
        ((uint4*)dst)[i] = u.v;
    }
}

// ---------------------------------------------------------------------------
// GEMM  C[M][1024] = A[M][K](bf16) * B[1024][K]^T (bf16, weights are [out][in])
// Triple-buffered LDS + 2-deep prefetch + counted vmcnt + A-panel XCD
// clustering + conflict-reduced rotated LDS layout (slot (u+(r>>1))&3).
// MODE 0 (BM=64, BN=128): plain fp32 write to outF
// MODE 1 (BM=BN=128): QKV fused, RoPE epilogue via LDS.
// ---------------------------------------------------------------------------
template <int MODE, int BM, int BN>
__global__ __launch_bounds__(256) void gemm_bt(
    const unsigned short* __restrict__ A,
    const unsigned short* __restrict__ B0,
    const unsigned short* __restrict__ B1,
    const unsigned short* __restrict__ B2,
    float* __restrict__ outF,
    unsigned short* __restrict__ Qh,
    unsigned short* __restrict__ Kh,
    unsigned short* __restrict__ Vt,
    const float2* __restrict__ tab,
    int M, int K)
{
    constexpr int PER_STAGE = (BM + BN) / 64;
    constexpr int WM = BM / 2, WN = BN / 2;
    constexpr int FM = WM / 16, FN = WN / 16;
    __shared__ __align__(16) unsigned short SM[3 * (BM + BN) * 32];

    const int lane = threadIdx.x & 63;
    const int wid  = threadIdx.x >> 6;
    const int l15 = lane & 15, lhi = lane >> 4;

    // ---- block swizzle decode: L = (y&7) + 8*(x + 8*(y>>3) + 32*z) ----
    const int L  = blockIdx.x;
    const int yl = L & 7;
    const int t  = L >> 3;
    const int bx = t & 7;
    const int t2 = t >> 3;
    int y, z;
    if constexpr (MODE == 1) { y = ((t2 & 3) << 3) | yl; z = t2 >> 2; }
    else                     { y = (t2 << 3) | yl;       z = 0;       }
    const int m0 = y * BM;
    const int n0 = bx * BN;
    const unsigned short* B = (z == 0) ? B0 : (z == 1) ? B1 : B2;
    const int waveM = (wid >> 1) * WM;
    const int waveN = (wid & 1) * WN;

    f32x4 acc[FM][FN];
    f32x4 zero = {0.f, 0.f, 0.f, 0.f};
#pragma unroll
    for (int m = 0; m < FM; ++m)
#pragma unroll
        for (int n = 0; n < FN; ++n) acc[m][n] = zero;

    const int lrow = lane >> 2;       // row within 16-row staging chunk
    const int uslot = lane & 3;       // dest 16B slot within row

    auto STAGE = [&](int buf, int k0) {
        unsigned short* as = SM + buf * (BM + BN) * 32;
        unsigned short* bs = as + BM * 32;
#pragma unroll
        for (int q = 0; q < BM / 64; ++q) {
            int rbase = wid * (BM / 4) + q * 16;
            int r = rbase + lrow;
            int ug = (uslot - (r >> 1)) & 3;   // rotated global source unit
            gload16(A + (size_t)(m0 + r) * K + k0 + ug * 8,
                    (char*)as + rbase * 64);
        }
#pragma unroll
        for (int q = 0; q < BN / 64; ++q) {
            int rbase = wid * (BN / 4) + q * 16;
            int r = rbase + lrow;
            int ug = (uslot - (r >> 1)) & 3;
            gload16(B + (size_t)(n0 + r) * K + k0 + ug * 8,
                    (char*)bs + rbase * 64);
        }
    };

    const int NK = K >> 5;            // 32 K-steps
    STAGE(0, 0);
    STAGE(1, 32);

    for (int k = 0; k < NK; ++k) {
        if (k < NK - 1) {
            if constexpr (PER_STAGE == 4) asm volatile("s_waitcnt vmcnt(4)" ::: "memory");
            else                          asm volatile("s_waitcnt vmcnt(3)" ::: "memory");
        } else {
            asm volatile("s_waitcnt vmcnt(0)" ::: "memory");
        }
        __builtin_amdgcn_s_barrier();
        __builtin_amdgcn_sched_barrier(0);
        if (k + 2 < NK) STAGE((k + 2) % 3, (k + 2) << 5);

        const unsigned short* as = SM + (k % 3) * (BM + BN) * 32;
        const unsigned short* bs = as + BM * 32;
        bf16x8 af[FM], bfr[FN];
#pragma unroll
        for (int m = 0; m < FM; ++m) {
            int ra = waveM + m * 16 + l15;
            af[m] = *(const bf16x8*)(as + ra * 32 + (((lhi + (ra >> 1)) & 3) << 3));
        }
#pragma unroll
        for (int n = 0; n < FN; ++n) {
            int rb = waveN + n * 16 + l15;
            bfr[n] = *(const bf16x8*)(bs + rb * 32 + (((lhi + (rb >> 1)) & 3) << 3));
        }
        __builtin_amdgcn_s_setprio(1);
#pragma unroll
        for (int m = 0; m < FM; ++m)
#pragma unroll
            for (int n = 0; n < FN; ++n)
                acc[m][n] = __builtin_amdgcn_mfma_f32_16x16x32_bf16(af[m], bfr[n], acc[m][n], 0, 0, 0);
        __builtin_amdgcn_s_setprio(0);
    }

    if constexpr (MODE == 0) {
#pragma unroll
        for (int n = 0; n < FN; ++n) {
            int col = n0 + waveN + n * 16 + l15;
#pragma unroll
            for (int m = 0; m < FM; ++m) {
                int rowb = m0 + waveM + m * 16 + (lhi << 2);
#pragma unroll
                for (int r = 0; r < 4; ++r)
                    outF[(size_t)(rowb + r) * D_MODEL + col] = acc[m][n][r];
            }
        }
    } else {
        __syncthreads();  // all waves done with stage buffers before aliasing
        unsigned short* Ct = ((unsigned short*)SM) + wid * 4608;  // 64x72/wave
        const int colg0 = n0 + waveN;
        const int hh    = (colg0 >> 6) & (NH - 1);
        const int rowg0 = m0 + waveM;
        const int bb    = rowg0 >> 11;
        const size_t bhh = (size_t)(bb * NH + hh);

#pragma unroll
        for (int n = 0; n < 4; ++n) {
            int cl = n * 16 + l15;
#pragma unroll
            for (int m = 0; m < 4; ++m) {
#pragma unroll
                for (int r = 0; r < 4; ++r) {
                    float v  = acc[m][n][r];
                    float pv = __shfl_xor(v, 1);
                    int rl = m * 16 + (lhi << 2) + r;
                    if (z == 2) {
                        Ct[cl * 72 + rl] = f2bf(v);
                    } else {
                        int ss = (rowg0 + rl) & (SEQ - 1);
                        float2 cs = tab[(ss << 5) + (cl >> 1)];
                        float o = (cl & 1) ? (pv * cs.y + v * cs.x)
                                           : (v * cs.x - pv * cs.y);
                        if (z == 0) o *= 0.18033688011f;  // (1/8)*log2(e)
                        Ct[rl * 72 + cl] = f2bf(o);
                    }
                }
            }
        }
        asm volatile("s_waitcnt lgkmcnt(0)" ::: "memory");

        const int lr = lane >> 3;
        const int lc = (lane & 7) << 3;
#pragma unroll
        for (int i = 0; i < 8; ++i) {
            int rl = i * 8 + lr;
            uint4 w = *(const uint4*)&Ct[rl * 72 + lc];
            if (z == 2) {
                int ss0 = rowg0 & (SEQ - 1);
                *(uint4*)(Vt + (bhh * DK + rl) * SEQ + ss0 + lc) = w;
            } else {
                int ss = (rowg0 + rl) & (SEQ - 1);
                unsigned short* dst = (z == 0) ? Qh : Kh;
                *(uint4*)(dst + (bhh * SEQ + ss) * DK + lc) = w;
            }
        }
    }
}

// ---------------------------------------------------------------------------
// causal flash attention v11: kv-128 tile (R6's proven addressing) + paired
// q-tiles (R8/R12's proven map) -> UNIFORM 17 iterations (was 33 at kv-64).
// Halves the serial per-block chain: per-iter fixed costs (2 barriers, vmcnt
// drain, max/sum shfls, P-LDS roundtrip latency) amortize over 2x work.
// 2-buffer K/V via global_load_lds, both-sides XOR swizzle, vmcnt(0)+barrier
// per iter (R7/R8 proven flow). P via LDS (R13's shfl version regressed).
// LDS 80 KB -> 2 blocks/CU (same residency as R12; pure chain-length bet).
// ---------------------------------------------------------------------------
__global__ __launch_bounds__(256) void attn_kernel(
    const unsigned short* __restrict__ Qh,
    const unsigned short* __restrict__ Kh,
    const unsigned short* __restrict__ Vt,
    unsigned short* __restrict__ O)
{
    __shared__ unsigned short Ks[2][128 * 64];   // 16 KB x2
    __shared__ unsigned short Vs[2][64 * 128];   // 16 KB x2
    __shared__ unsigned short P[4][16 * 128];    // 16 KB

    const int tid  = threadIdx.x;
    const int lane = tid & 63;
    const int wid  = tid >> 6;
    const int l15 = lane & 15, lhi = lane >> 4;

    const int L   = blockIdx.x;
    const int xcd = L & 7;
    const int r0  = L >> 3;              // 0..63
    const int bh  = (xcd << 2) | (r0 & 3);
    const int pi  = r0 >> 2;             // 0..15
    const int b = bh >> 4, h = bh & 15;

    const unsigned short* Qb = Qh + (size_t)bh * SEQ * DK;
    const unsigned short* Kb = Kh + (size_t)bh * SEQ * DK;
    const unsigned short* Vb = Vt + (size_t)bh * DK * SEQ;

    const int NT0 = (pi >> 1) + 1;       // 128-kv tiles in phase 0
    const int NTT = 17;                  // total tiles (uniform for all blocks)

    auto kv_of = [&](int g) { return (g < NT0 ? g : g - NT0) << 7; };

    // stage one 128-kv tile: K 128x64 + V 64x128 (R6's exact addressing)
    auto STAGE = [&](int buf, int kv0s) {
#pragma unroll
        for (int c = 0; c < 4; ++c) {
            int ub = c * 256 + wid * 64;   // wave-uniform unit base
            int u  = ub + lane;
            int kr = u >> 3;               // K row (0..127)
            int kc = (u & 7) ^ (kr & 7);
            gload16(Kb + (size_t)(kv0s + kr) * DK + kc * 8, &Ks[buf][(size_t)ub * 8]);
            int vr = u >> 4;               // V d-row (0..63)
            int vc = (u & 15) ^ (vr & 7);
            gload16(Vb + (size_t)vr * SEQ + kv0s + vc * 8, &Vs[buf][(size_t)ub * 8]);
        }
    };

    const f32x4 zero = {0.f, 0.f, 0.f, 0.f};
    const f32x4 ninf = {-1e30f, -1e30f, -1e30f, -1e30f};
    const int sw = l15 & 7;

    STAGE(0, 0);
    int g = 0;

    for (int ph = 0; ph < 2; ++ph) {
        const int qt = ph ? (31 - pi) : pi;
        const int q0 = qt << 6;
        const int qw = q0 + wid * 16;
        const int ktl = qt >> 1;           // last 128-kv tile index

        bf16x8 qf[2];
#pragma unroll
        for (int kk = 0; kk < 2; ++kk)
            qf[kk] = *(const bf16x8*)(Qb + (size_t)(qw + l15) * DK + kk * 32 + lhi * 8);

        f32x4 oacc[4];
#pragma unroll
        for (int nd = 0; nd < 4; ++nd) oacc[nd] = zero;
        float mrow = -1e30f;
        float lrow = 0.f;

        for (int kt = 0; kt <= ktl; ++kt, ++g) {
            const int kv0 = kt << 7;
            const bool diag = (kt == ktl);
            const int nlim = diag ? (((qw - kv0) >> 4) + 1) : 8;

            asm volatile("s_waitcnt vmcnt(0)" ::: "memory");
            __builtin_amdgcn_s_barrier();
            __builtin_amdgcn_sched_barrier(0);
            if (g + 1 < NTT) STAGE((g + 1) & 1, kv_of(g + 1));

            const unsigned short* Kc = Ks[g & 1];
            const unsigned short* Vc = Vs[g & 1];

            f32x4 s[8];  // s[n][r]: kv = kv0 + n*16 + lhi*4 + r, q = qw + l15
#pragma unroll
            for (int n = 0; n < 8; ++n) s[n] = (n < nlim) ? zero : ninf;

            __builtin_amdgcn_s_setprio(1);
#pragma unroll
            for (int n = 0; n < 8; ++n) {
                if (n < nlim) {
                    int rr = n * 16 + l15;
                    bf16x8 k0 = *(const bf16x8*)&Kc[rr * 64 + ((lhi ^ sw) << 3)];
                    bf16x8 k1 = *(const bf16x8*)&Kc[rr * 64 + (((4 + lhi) ^ sw) << 3)];
                    s[n] = __builtin_amdgcn_mfma_f32_16x16x32_bf16(k0, qf[0], s[n], 0, 0, 0);
                    s[n] = __builtin_amdgcn_mfma_f32_16x16x32_bf16(k1, qf[1], s[n], 0, 0, 0);
                }
            }
            __builtin_amdgcn_s_setprio(0);

            if (diag) {  // causal: mask kv > q
                const int qg = qw + l15;
#pragma unroll
                for (int n = 0; n < 8; ++n) {
                    if (n < nlim) {
#pragma unroll
                        for (int rr = 0; rr < 4; ++rr) {
                            int kg = kv0 + n * 16 + (lhi << 2) + rr;
                            if (kg > qg) s[n][rr] = -1e30f;
                        }
                    }
                }
            }

            float mx = fmaxf(fmaxf(s[0][0], s[0][1]), fmaxf(s[0][2], s[0][3]));
#pragma unroll
            for (int n = 1; n < 8; ++n)
                mx = fmaxf(mx, fmaxf(fmaxf(s[n][0], s[n][1]), fmaxf(s[n][2], s[n][3])));
            mx = fmaxf(mx, __shfl_xor(mx, 16));
            mx = fmaxf(mx, __shfl_xor(mx, 32));

            float alpha = 1.f;
            const int allDefer = __all(mx <= mrow + 8.f);
            if (!allDefer) {
                float mn = fmaxf(mrow, mx);
                alpha = __builtin_amdgcn_exp2f(mrow - mn);
                mrow = mn;
            }

#pragma unroll
            for (int n = 0; n < 8; ++n)
#pragma unroll
                for (int rr = 0; rr < 4; ++rr)
                    s[n][rr] = __builtin_amdgcn_exp2f(s[n][rr] - mrow);

            float rs = 0.f;
#pragma unroll
            for (int n = 0; n < 8; ++n)
                rs += (s[n][0] + s[n][1]) + (s[n][2] + s[n][3]);
            rs += __shfl_xor(rs, 16);
            rs += __shfl_xor(rs, 32);
            lrow = allDefer ? (lrow + rs) : (lrow * alpha + rs);

            // P -> LDS: cvt_pk pairs + ds_write_b64, XOR-swizzled (R6 layout)
#pragma unroll
            for (int n = 0; n < 8; ++n) {
                uint2 pk;
                pk.x = cvtpk(s[n][0], s[n][1]);
                pk.y = cvtpk(s[n][2], s[n][3]);
                int cW = 2 * n + (lhi >> 1);
                *(uint2*)&P[wid][(l15 << 7) + ((cW ^ l15) << 3) + ((lhi & 1) << 2)] = pk;
            }

            if (!allDefer) {
                float a0 = __shfl(alpha, (lhi << 2) + 0);
                float a1 = __shfl(alpha, (lhi << 2) + 1);
                float a2 = __shfl(alpha, (lhi << 2) + 2);
                float a3 = __shfl(alpha, (lhi << 2) + 3);
#pragma unroll
                for (int nd = 0; nd < 4; ++nd) {
                    oacc[nd][0] *= a0; oacc[nd][1] *= a1;
                    oacc[nd][2] *= a2; oacc[nd][3] *= a3;
                }
            }

            asm volatile("s_waitcnt lgkmcnt(0)" ::: "memory");
            const int kklim = diag ? ((nlim + 1) >> 1) : 4;
            bf16x8 pa[4];
#pragma unroll
            for (int kk = 0; kk < 4; ++kk)
                if (kk < kklim)
                    pa[kk] = *(const bf16x8*)&P[wid][(l15 << 7) + ((((kk << 2) + lhi) ^ l15) << 3)];

            __builtin_amdgcn_s_setprio(1);
#pragma unroll
            for (int nd = 0; nd < 4; ++nd)
#pragma unroll
                for (int kk = 0; kk < 4; ++kk)
                    if (kk < kklim) {
                        int rd = nd * 16 + l15;
                        bf16x8 vf = *(const bf16x8*)&Vc[rd * 128 + ((((kk << 2) + lhi) ^ sw) << 3)];
                        oacc[nd] = __builtin_amdgcn_mfma_f32_16x16x32_bf16(pa[kk], vf, oacc[nd], 0, 0, 0);
                    }
            __builtin_amdgcn_s_setprio(0);
        }

        float inv = 1.f / lrow;
        float i0 = __shfl(inv, (lhi << 2) + 0);
        float i1 = __shfl(inv, (lhi << 2) + 1);
        float i2 = __shfl(inv, (lhi << 2) + 2);
        float i3 = __shfl(inv, (lhi << 2) + 3);
#pragma unroll
        for (int nd = 0; nd < 4; ++nd) {
            int d = nd * 16 + l15;
            int rowb = qw + (lhi << 2);
            O[((size_t)(b * SEQ + rowb + 0)) * D_MODEL + h * DK + d] = f2bf(oacc[nd][0] * i0);
            O[((size_t)(b * SEQ + rowb + 1)) * D_MODEL + h * DK + d] = f2bf(oacc[nd][1] * i1);
            O[((size_t)(b * SEQ + rowb + 2)) * D_MODEL + h * DK + d] = f2bf(oacc[nd][2] * i2);
            O[((size_t)(b * SEQ + rowb + 3)) * D_MODEL + h * DK + d] = f2bf(oacc[nd][3] * i3);
        }
    }
}

// ---------------------------------------------------------------------------
extern "C" void kernel_launch(void* const* d_in, const int* in_sizes, int n_in,
                              void* d_out, int out_size, void* d_ws, size_t ws_size,
                              hipStream_t stream)
{
    const float* x  = (const float*)d_in[0];
    const float* Wq = (const float*)d_in[1];
    const float* Wk = (const float*)d_in[2];
    const float* Wv = (const float*)d_in[3];
    const float* Wo = (const float*)d_in[4];
    float* out = (float*)d_out;

    char* ws = (char*)d_ws;
    unsigned short* xb  = (unsigned short*)(ws);                    // 8 MB (reused as attn buf)
    unsigned short* Wqb = (unsigned short*)(ws + ( 8ull << 20));
    unsigned short* Wkb = (unsigned short*)(ws + (10ull << 20));
    unsigned short* Wvb = (unsigned short*)(ws + (12ull << 20));
    unsigned short* Wob = (unsigned short*)(ws + (14ull << 20));
    unsigned short* Qh  = (unsigned short*)(ws + (16ull << 20));    // [bh][s][64]
    unsigned short* Kh  = (unsigned short*)(ws + (24ull << 20));    // [bh][s][64]
    unsigned short* Vt  = (unsigned short*)(ws + (32ull << 20));    // [bh][64][s]
    float2*         tab = (float2*)(ws + (40ull << 20));            // 512 KB RoPE table
    unsigned short* attn = xb;

    cast5<<<dim3(512, 6), 256, 0, stream>>>(x, Wq, Wk, Wv, Wo, xb, Wqb, Wkb, Wvb, Wob, tab);

    gemm_bt<1, 128, 128><<<768, 256, 0, stream>>>(
        xb, Wqb, Wkb, Wvb, nullptr, Qh, Kh, Vt, tab, NB * SEQ, D_MODEL);

    attn_kernel<<<512, 256, 0, stream>>>(Qh, Kh, Vt, attn);

    gemm_bt<0, 64, 128><<<512, 256, 0, stream>>>(
        attn, Wob, Wob, Wob, out, nullptr, nullptr, nullptr, nullptr, NB * SEQ, D_MODEL);
}

// Round 15
// 117.185 us; speedup vs baseline: 1.0799x; 1.0799x over previous
//
#include <hip/hip_runtime.h>

typedef float f32x4 __attribute__((ext_vector_type(4)));
typedef __bf16 bf16x8 __attribute__((ext_vector_type(8)));

#define D_MODEL 1024
#define SEQ     2048
#define NB      2
#define NH      16
#define DK      64

__device__ __forceinline__ unsigned short f2bf(float f) {
    union { float f; unsigned int u; } un; un.f = f;
    unsigned int r = un.u + 0x7fffu + ((un.u >> 16) & 1u);
    return (unsigned short)(r >> 16);
}

__device__ __forceinline__ unsigned cvtpk(float lo, float hi) {
    unsigned r;
    asm("v_cvt_pk_bf16_f32 %0, %1, %2" : "=v"(r) : "v"(lo), "v"(hi));
    return r;
}

__device__ __forceinline__ void gload16(const void* g, void* l) {
    __builtin_amdgcn_global_load_lds((__attribute__((address_space(1))) void*)g,
                                     (__attribute__((address_space(3))) void*)l,
                                     16, 0, 0);
}

// ---------------------------------------------------------------------------
// fused fp32 -> bf16 casts for x and the 4 weights + RoPE cos/sin table
// ---------------------------------------------------------------------------
__global__ __launch_bounds__(256) void cast5(
    const float* __restrict__ x,  const float* __restrict__ wq,
    const float* __restrict__ wk, const float* __restrict__ wv,
    const float* __restrict__ wo,
    unsigned short* __restrict__ xb,  unsigned short* __restrict__ wqb,
    unsigned short* __restrict__ wkb, unsigned short* __restrict__ wvb,
    unsigned short* __restrict__ wob, float2* __restrict__ tab)
{
    if (blockIdx.y == 5) {  // RoPE table: [ss][p] -> (cos, sin), p = d/2 index
        int idx = blockIdx.x * 256 + threadIdx.x;
        if (idx < SEQ * 32) {
            int ss = idx >> 5, p = idx & 31;
            float freq = exp2f(-0.41524101186f * (float)p);  // 10000^(-p/32)
            float sn, cs;
            sincosf((float)ss * freq, &sn, &cs);
            tab[idx] = make_float2(cs, sn);
        }
        return;
    }
    const float* src; unsigned short* dst; int n8;
    switch (blockIdx.y) {
        case 0:  src = x;  dst = xb;  n8 = (NB*SEQ*D_MODEL)/8; break;
        case 1:  src = wq; dst = wqb; n8 = (D_MODEL*D_MODEL)/8; break;
        case 2:  src = wk; dst = wkb; n8 = (D_MODEL*D_MODEL)/8; break;
        case 3:  src = wv; dst = wvb; n8 = (D_MODEL*D_MODEL)/8; break;
        default: src = wo; dst = wob; n8 = (D_MODEL*D_MODEL)/8; break;
    }
    int stride = gridDim.x * blockDim.x;
    for (int i = blockIdx.x * blockDim.x + threadIdx.x; i < n8; i += stride) {
        const float4* p = (const float4*)src + (size_t)i * 2;
        float4 a = p[0], b = p[1];
        union { unsigned short h[8]; uint4 v; } u;
        u.h[0] = f2bf(a.x); u.h[1] = f2bf(a.y); u.h[2] = f2bf(a.z); u.h[3] = f2bf(a.w);
        u.h[4] = f2bf(b.x); u.h[5] = f2bf(b.y); u.h[6] = f2bf(b.z); u.h[7] = f2bf(b.w);
        ((uint4*)dst)[i] = u.v;
    }
}

// ---------------------------------------------------------------------------
// GEMM (unchanged from R12): triple-buffered LDS + 2-deep prefetch + counted
// vmcnt + A-panel XCD clustering + rotated conflict-reduced LDS layout.
// ---------------------------------------------------------------------------
template <int MODE, int BM, int BN>
__global__ __launch_bounds__(256) void gemm_bt(
    const unsigned short* __restrict__ A,
    const unsigned short* __restrict__ B0,
    const unsigned short* __restrict__ B1,
    const unsigned short* __restrict__ B2,
    float* __restrict__ outF,
    unsigned short* __restrict__ Qh,
    unsigned short* __restrict__ Kh,
    unsigned short* __restrict__ Vt,
    const float2* __restrict__ tab,
    int M, int K)
{
    constexpr int PER_STAGE = (BM + BN) / 64;
    constexpr int WM = BM / 2, WN = BN / 2;
    constexpr int FM = WM / 16, FN = WN / 16;
    __shared__ __align__(16) unsigned short SM[3 * (BM + BN) * 32];

    const int lane = threadIdx.x & 63;
    const int wid  = threadIdx.x >> 6;
    const int l15 = lane & 15, lhi = lane >> 4;

    const int L  = blockIdx.x;
    const int yl = L & 7;
    const int t  = L >> 3;
    const int bx = t & 7;
    const int t2 = t >> 3;
    int y, z;
    if constexpr (MODE == 1) { y = ((t2 & 3) << 3) | yl; z = t2 >> 2; }
    else                     { y = (t2 << 3) | yl;       z = 0;       }
    const int m0 = y * BM;
    const int n0 = bx * BN;
    const unsigned short* B = (z == 0) ? B0 : (z == 1) ? B1 : B2;
    const int waveM = (wid >> 1) * WM;
    const int waveN = (wid & 1) * WN;

    f32x4 acc[FM][FN];
    f32x4 zero = {0.f, 0.f, 0.f, 0.f};
#pragma unroll
    for (int m = 0; m < FM; ++m)
#pragma unroll
        for (int n = 0; n < FN; ++n) acc[m][n] = zero;

    const int lrow = lane >> 2;
    const int uslot = lane & 3;

    auto STAGE = [&](int buf, int k0) {
        unsigned short* as = SM + buf * (BM + BN) * 32;
        unsigned short* bs = as + BM * 32;
#pragma unroll
        for (int q = 0; q < BM / 64; ++q) {
            int rbase = wid * (BM / 4) + q * 16;
            int r = rbase + lrow;
            int ug = (uslot - (r >> 1)) & 3;
            gload16(A + (size_t)(m0 + r) * K + k0 + ug * 8,
                    (char*)as + rbase * 64);
        }
#pragma unroll
        for (int q = 0; q < BN / 64; ++q) {
            int rbase = wid * (BN / 4) + q * 16;
            int r = rbase + lrow;
            int ug = (uslot - (r >> 1)) & 3;
            gload16(B + (size_t)(n0 + r) * K + k0 + ug * 8,
                    (char*)bs + rbase * 64);
        }
    };

    const int NK = K >> 5;
    STAGE(0, 0);
    STAGE(1, 32);

    for (int k = 0; k < NK; ++k) {
        if (k < NK - 1) {
            if constexpr (PER_STAGE == 4) asm volatile("s_waitcnt vmcnt(4)" ::: "memory");
            else                          asm volatile("s_waitcnt vmcnt(3)" ::: "memory");
        } else {
            asm volatile("s_waitcnt vmcnt(0)" ::: "memory");
        }
        __builtin_amdgcn_s_barrier();
        __builtin_amdgcn_sched_barrier(0);
        if (k + 2 < NK) STAGE((k + 2) % 3, (k + 2) << 5);

        const unsigned short* as = SM + (k % 3) * (BM + BN) * 32;
        const unsigned short* bs = as + BM * 32;
        bf16x8 af[FM], bfr[FN];
#pragma unroll
        for (int m = 0; m < FM; ++m) {
            int ra = waveM + m * 16 + l15;
            af[m] = *(const bf16x8*)(as + ra * 32 + (((lhi + (ra >> 1)) & 3) << 3));
        }
#pragma unroll
        for (int n = 0; n < FN; ++n) {
            int rb = waveN + n * 16 + l15;
            bfr[n] = *(const bf16x8*)(bs + rb * 32 + (((lhi + (rb >> 1)) & 3) << 3));
        }
        __builtin_amdgcn_s_setprio(1);
#pragma unroll
        for (int m = 0; m < FM; ++m)
#pragma unroll
            for (int n = 0; n < FN; ++n)
                acc[m][n] = __builtin_amdgcn_mfma_f32_16x16x32_bf16(af[m], bfr[n], acc[m][n], 0, 0, 0);
        __builtin_amdgcn_s_setprio(0);
    }

    if constexpr (MODE == 0) {
#pragma unroll
        for (int n = 0; n < FN; ++n) {
            int col = n0 + waveN + n * 16 + l15;
#pragma unroll
            for (int m = 0; m < FM; ++m) {
                int rowb = m0 + waveM + m * 16 + (lhi << 2);
#pragma unroll
                for (int r = 0; r < 4; ++r)
                    outF[(size_t)(rowb + r) * D_MODEL + col] = acc[m][n][r];
            }
        }
    } else {
        __syncthreads();
        unsigned short* Ct = ((unsigned short*)SM) + wid * 4608;
        const int colg0 = n0 + waveN;
        const int hh    = (colg0 >> 6) & (NH - 1);
        const int rowg0 = m0 + waveM;
        const int bb    = rowg0 >> 11;
        const size_t bhh = (size_t)(bb * NH + hh);

#pragma unroll
        for (int n = 0; n < 4; ++n) {
            int cl = n * 16 + l15;
#pragma unroll
            for (int m = 0; m < 4; ++m) {
#pragma unroll
                for (int r = 0; r < 4; ++r) {
                    float v  = acc[m][n][r];
                    float pv = __shfl_xor(v, 1);
                    int rl = m * 16 + (lhi << 2) + r;
                    if (z == 2) {
                        Ct[cl * 72 + rl] = f2bf(v);
                    } else {
                        int ss = (rowg0 + rl) & (SEQ - 1);
                        float2 cs = tab[(ss << 5) + (cl >> 1)];
                        float o = (cl & 1) ? (pv * cs.y + v * cs.x)
                                           : (v * cs.x - pv * cs.y);
                        if (z == 0) o *= 0.18033688011f;  // (1/8)*log2(e)
                        Ct[rl * 72 + cl] = f2bf(o);
                    }
                }
            }
        }
        asm volatile("s_waitcnt lgkmcnt(0)" ::: "memory");

        const int lr = lane >> 3;
        const int lc = (lane & 7) << 3;
#pragma unroll
        for (int i = 0; i < 8; ++i) {
            int rl = i * 8 + lr;
            uint4 w = *(const uint4*)&Ct[rl * 72 + lc];
            if (z == 2) {
                int ss0 = rowg0 & (SEQ - 1);
                *(uint4*)(Vt + (bhh * DK + rl) * SEQ + ss0 + lc) = w;
            } else {
                int ss = (rowg0 + rl) & (SEQ - 1);
                unsigned short* dst = (z == 0) ? Qh : Kh;
                *(uint4*)(dst + (bhh * SEQ + ss) * DK + lc) = w;
            }
        }
    }
}

// ---------------------------------------------------------------------------
// causal flash attention v12: SPLIT-K for 4 blocks/CU sustained occupancy.
// 1024 uniform blocks: pair (pi,31-pi)'s 33-tile kv stream split at 17:
//   j=0 (17 iters): all of qt=pi (final write) + kv tiles 0..15-pi of
//                   qt=31-pi (partial A -> d_out scratch)
//   j=1 (16 iters): kv tiles 16-pi..31-pi of qt=31-pi (partial B -> ws)
// Partials (unnormalized O f32 + m,l) merged by attn_merge via online-
// softmax algebra. Inner body = R12 verbatim (kv-64, both-sides XOR swizzle,
// cvt_pk P-LDS, defer-max); 2-buf staging (R8's proven vmcnt(0) flow).
// LDS = 16+16+8 = 40 KB -> exactly 4 blocks/CU; grid 1024 = exactly 4/CU.
// ---------------------------------------------------------------------------
__global__ __launch_bounds__(256) void attn_kernel(
    const unsigned short* __restrict__ Qh,
    const unsigned short* __restrict__ Kh,
    const unsigned short* __restrict__ Vt,
    unsigned short* __restrict__ O,
    float* __restrict__ paO, float2* __restrict__ paM,
    float* __restrict__ pbO, float2* __restrict__ pbM)
{
    __shared__ unsigned short Ks[2][64 * 64];   // 8 KB x2
    __shared__ unsigned short Vs[2][64 * 64];   // 8 KB x2
    __shared__ unsigned short P[4][16 * 64];    // 8 KB

    const int tid  = threadIdx.x;
    const int lane = tid & 63;
    const int wid  = tid >> 6;
    const int l15 = lane & 15, lhi = lane >> 4;

    const int L    = blockIdx.x;
    const int xcd  = L & 7;
    const int r0   = L >> 3;             // 0..127
    const int bh   = (xcd << 2) | (r0 & 3);
    const int rest = r0 >> 2;            // 0..31
    const int pi   = rest & 15;
    const int j    = rest >> 4;          // 0 or 1 (j=0 dispatched first)
    const int b = bh >> 4, h = bh & 15;
    const size_t p = (size_t)bh * 16 + (15 - pi);  // partial slot for qt=31-pi

    const unsigned short* Qb = Qh + (size_t)bh * SEQ * DK;
    const unsigned short* Kb = Kh + (size_t)bh * SEQ * DK;
    const unsigned short* Vb = Vt + (size_t)bh * DK * SEQ;

    const int NT = j ? 16 : 17;          // uniform iters

    // global staging index g -> true kv tile index
    auto kv_of = [&](int g) {
        if (j) return 16 - pi + g;
        return (g <= pi) ? g : g - (pi + 1);
    };

    auto STAGE = [&](int buf, int kvt) {
        int kv0s = kvt << 6;
#pragma unroll
        for (int c = 0; c < 2; ++c) {
            int ub = c * 256 + wid * 64;
            int u  = ub + lane;
            int kr = u >> 3;
            int kc = (u & 7) ^ (kr & 7);
            gload16(Kb + (size_t)(kv0s + kr) * DK + kc * 8, &Ks[buf][(size_t)ub * 8]);
            gload16(Vb + (size_t)kr * SEQ + kv0s + kc * 8, &Vs[buf][(size_t)ub * 8]);
        }
    };

    const f32x4 zero = {0.f, 0.f, 0.f, 0.f};
    const f32x4 ninf = {-1e30f, -1e30f, -1e30f, -1e30f};
    const int sw = l15 & 7;

    STAGE(0, kv_of(0));
    int g = 0;

    const int nph = j ? 1 : 2;
    for (int ph = 0; ph < nph; ++ph) {
        // phase parameters
        int qt, ktbeg, ktend, dodiag, finalw;
        if (j == 0 && ph == 0) { qt = pi;      ktbeg = 0;       ktend = pi;      dodiag = 1; finalw = 1; }
        else if (j == 0)       { qt = 31 - pi; ktbeg = 0;       ktend = 15 - pi; dodiag = 0; finalw = 0; }
        else                   { qt = 31 - pi; ktbeg = 16 - pi; ktend = 31 - pi; dodiag = 1; finalw = 0; }

        const int q0 = qt << 6;
        const int qw = q0 + wid * 16;

        bf16x8 qf[2];
#pragma unroll
        for (int kk = 0; kk < 2; ++kk)
            qf[kk] = *(const bf16x8*)(Qb + (size_t)(qw + l15) * DK + kk * 32 + lhi * 8);

        f32x4 oacc[4];
#pragma unroll
        for (int nd = 0; nd < 4; ++nd) oacc[nd] = zero;
        float mrow = -1e30f;
        float lrow = 0.f;

        for (int kt = ktbeg; kt <= ktend; ++kt, ++g) {
            const int kv0 = kt << 6;
            const bool diag = dodiag && (kt == ktend);
            const int nlim = diag ? (wid + 1) : 4;

            asm volatile("s_waitcnt vmcnt(0)" ::: "memory");
            __builtin_amdgcn_s_barrier();
            __builtin_amdgcn_sched_barrier(0);
            if (g + 1 < NT) STAGE((g + 1) & 1, kv_of(g + 1));

            const unsigned short* Kc = Ks[g & 1];
            const unsigned short* Vc = Vs[g & 1];

            f32x4 s[4];
#pragma unroll
            for (int n = 0; n < 4; ++n) s[n] = (n < nlim) ? zero : ninf;

            __builtin_amdgcn_s_setprio(1);
#pragma unroll
            for (int n = 0; n < 4; ++n) {
                if (n < nlim) {
                    int rr = n * 16 + l15;
                    bf16x8 k0 = *(const bf16x8*)&Kc[rr * 64 + ((lhi ^ sw) << 3)];
                    bf16x8 k1 = *(const bf16x8*)&Kc[rr * 64 + (((4 + lhi) ^ sw) << 3)];
                    s[n] = __builtin_amdgcn_mfma_f32_16x16x32_bf16(k0, qf[0], s[n], 0, 0, 0);
                    s[n] = __builtin_amdgcn_mfma_f32_16x16x32_bf16(k1, qf[1], s[n], 0, 0, 0);
                }
            }
            __builtin_amdgcn_s_setprio(0);

            if (diag) {
                const int qg = qw + l15;
#pragma unroll
                for (int n = 0; n < 4; ++n) {
                    if (n < nlim) {
#pragma unroll
                        for (int rr = 0; rr < 4; ++rr) {
                            int kg = kv0 + n * 16 + (lhi << 2) + rr;
                            if (kg > qg) s[n][rr] = -1e30f;
                        }
                    }
                }
            }

            float mx = fmaxf(fmaxf(s[0][0], s[0][1]), fmaxf(s[0][2], s[0][3]));
#pragma unroll
            for (int n = 1; n < 4; ++n)
                mx = fmaxf(mx, fmaxf(fmaxf(s[n][0], s[n][1]), fmaxf(s[n][2], s[n][3])));
            mx = fmaxf(mx, __shfl_xor(mx, 16));
            mx = fmaxf(mx, __shfl_xor(mx, 32));

            float alpha = 1.f;
            const int allDefer = __all(mx <= mrow + 8.f);
            if (!allDefer) {
                float mn = fmaxf(mrow, mx);
                alpha = __builtin_amdgcn_exp2f(mrow - mn);
                mrow = mn;
            }

#pragma unroll
            for (int n = 0; n < 4; ++n)
#pragma unroll
                for (int rr = 0; rr < 4; ++rr)
                    s[n][rr] = __builtin_amdgcn_exp2f(s[n][rr] - mrow);

            float rs = 0.f;
#pragma unroll
            for (int n = 0; n < 4; ++n)
                rs += (s[n][0] + s[n][1]) + (s[n][2] + s[n][3]);
            rs += __shfl_xor(rs, 16);
            rs += __shfl_xor(rs, 32);
            lrow = allDefer ? (lrow + rs) : (lrow * alpha + rs);

#pragma unroll
            for (int n = 0; n < 4; ++n) {
                uint2 pk;
                pk.x = cvtpk(s[n][0], s[n][1]);
                pk.y = cvtpk(s[n][2], s[n][3]);
                int cW = 2 * n + (lhi >> 1);
                *(uint2*)&P[wid][(l15 << 6) + ((cW ^ sw) << 3) + ((lhi & 1) << 2)] = pk;
            }

            if (!allDefer) {
                float a0 = __shfl(alpha, (lhi << 2) + 0);
                float a1 = __shfl(alpha, (lhi << 2) + 1);
                float a2 = __shfl(alpha, (lhi << 2) + 2);
                float a3 = __shfl(alpha, (lhi << 2) + 3);
#pragma unroll
                for (int nd = 0; nd < 4; ++nd) {
                    oacc[nd][0] *= a0; oacc[nd][1] *= a1;
                    oacc[nd][2] *= a2; oacc[nd][3] *= a3;
                }
            }

            asm volatile("s_waitcnt lgkmcnt(0)" ::: "memory");
            const int kklim = diag ? ((nlim + 1) >> 1) : 2;
            bf16x8 pa[2];
#pragma unroll
            for (int kk = 0; kk < 2; ++kk)
                if (kk < kklim)
                    pa[kk] = *(const bf16x8*)&P[wid][(l15 << 6) + ((((kk << 2) + lhi) ^ sw) << 3)];

            __builtin_amdgcn_s_setprio(1);
#pragma unroll
            for (int nd = 0; nd < 4; ++nd)
#pragma unroll
                for (int kk = 0; kk < 2; ++kk)
                    if (kk < kklim) {
                        int rd = nd * 16 + l15;
                        bf16x8 vf = *(const bf16x8*)&Vc[rd * 64 + ((((kk << 2) + lhi) ^ sw) << 3)];
                        oacc[nd] = __builtin_amdgcn_mfma_f32_16x16x32_bf16(pa[kk], vf, oacc[nd], 0, 0, 0);
                    }
            __builtin_amdgcn_s_setprio(0);
        }

        if (finalw) {
            float inv = 1.f / lrow;
            float i0 = __shfl(inv, (lhi << 2) + 0);
            float i1 = __shfl(inv, (lhi << 2) + 1);
            float i2 = __shfl(inv, (lhi << 2) + 2);
            float i3 = __shfl(inv, (lhi << 2) + 3);
#pragma unroll
            for (int nd = 0; nd < 4; ++nd) {
                int d = nd * 16 + l15;
                int rowb = qw + (lhi << 2);
                O[((size_t)(b * SEQ + rowb + 0)) * D_MODEL + h * DK + d] = f2bf(oacc[nd][0] * i0);
                O[((size_t)(b * SEQ + rowb + 1)) * D_MODEL + h * DK + d] = f2bf(oacc[nd][1] * i1);
                O[((size_t)(b * SEQ + rowb + 2)) * D_MODEL + h * DK + d] = f2bf(oacc[nd][2] * i2);
                O[((size_t)(b * SEQ + rowb + 3)) * D_MODEL + h * DK + d] = f2bf(oacc[nd][3] * i3);
            }
        } else {
            // unnormalized partial: O tile (f32) + per-row (m, l)
            float*  PO = (j ? pbO : paO) + p * 4096;
            float2* PM = (j ? pbM : paM) + p * 64;
#pragma unroll
            for (int nd = 0; nd < 4; ++nd)
#pragma unroll
                for (int rr = 0; rr < 4; ++rr) {
                    int rowl = wid * 16 + (lhi << 2) + rr;
                    PO[rowl * 64 + nd * 16 + l15] = oacc[nd][rr];
                }
            if (lhi == 0)
                PM[wid * 16 + l15] = make_float2(mrow, lrow);
        }
    }
}

// ---------------------------------------------------------------------------
// merge two partials per split q-tile (qhi = 16..31) via online-softmax
// algebra: m = max(m1,m2); O = (O1*e^(m1-m) + O2*e^(m2-m)) / (l1*a1 + l2*a2)
// ---------------------------------------------------------------------------
__global__ __launch_bounds__(256) void attn_merge(
    const float* __restrict__ paO, const float2* __restrict__ paM,
    const float* __restrict__ pbO, const float2* __restrict__ pbM,
    unsigned short* __restrict__ O)
{
    const int mb = blockIdx.x;          // 0..511
    const int bh = mb >> 4, qq = mb & 15;
    const int b = bh >> 4, h = bh & 15;
    const int q0 = (16 + qq) << 6;
    const size_t p = (size_t)bh * 16 + qq;
    const int t = threadIdx.x;
    const int r = t >> 2;               // row 0..63
    const int c0 = (t & 3) << 4;        // col base 0/16/32/48

    float2 ma = paM[p * 64 + r];
    float2 mbv = pbM[p * 64 + r];
    float m = fmaxf(ma.x, mbv.x);
    float a1 = __builtin_amdgcn_exp2f(ma.x - m);
    float a2 = __builtin_amdgcn_exp2f(mbv.x - m);
    float inv = 1.f / (ma.y * a1 + mbv.y * a2);

    const float* o1 = paO + p * 4096 + r * 64 + c0;
    const float* o2 = pbO + p * 4096 + r * 64 + c0;
    union { unsigned short hh[16]; uint4 v[2]; } u;
#pragma unroll
    for (int c = 0; c < 16; ++c)
        u.hh[c] = f2bf((o1[c] * a1 + o2[c] * a2) * inv);
    uint4* dst = (uint4*)(O + ((size_t)(b * SEQ + q0 + r)) * D_MODEL + h * DK + c0);
    dst[0] = u.v[0];
    dst[1] = u.v[1];
}

// ---------------------------------------------------------------------------
extern "C" void kernel_launch(void* const* d_in, const int* in_sizes, int n_in,
                              void* d_out, int out_size, void* d_ws, size_t ws_size,
                              hipStream_t stream)
{
    const float* x  = (const float*)d_in[0];
    const float* Wq = (const float*)d_in[1];
    const float* Wk = (const float*)d_in[2];
    const float* Wv = (const float*)d_in[3];
    const float* Wo = (const float*)d_in[4];
    float* out = (float*)d_out;

    char* ws = (char*)d_ws;
    unsigned short* xb  = (unsigned short*)(ws);                    // 8 MB (reused as attn buf)
    unsigned short* Wqb = (unsigned short*)(ws + ( 8ull << 20));
    unsigned short* Wkb = (unsigned short*)(ws + (10ull << 20));
    unsigned short* Wvb = (unsigned short*)(ws + (12ull << 20));
    unsigned short* Wob = (unsigned short*)(ws + (14ull << 20));
    unsigned short* Qh  = (unsigned short*)(ws + (16ull << 20));    // [bh][s][64]
    unsigned short* Kh  = (unsigned short*)(ws + (24ull << 20));    // [bh][s][64]
    unsigned short* Vt  = (unsigned short*)(ws + (32ull << 20));    // [bh][64][s]
    float2*         tab = (float2*)(ws + (40ull << 20));            // 512 KB RoPE table
    unsigned short* attn = xb;

    // split-K partials: set A in d_out (scratch until gemm0 overwrites it),
    // set B in ws. 512 slots x (64x64 f32 O + 64 x (m,l)).
    float*  paO = out;                                   // 8 MB
    float2* paM = (float2*)(out + 512 * 4096);           // 256 KB
    float*  pbO = (float*)(ws + (41ull << 20));          // 8 MB
    float2* pbM = (float2*)(ws + (49ull << 20));         // 256 KB

    cast5<<<dim3(512, 6), 256, 0, stream>>>(x, Wq, Wk, Wv, Wo, xb, Wqb, Wkb, Wvb, Wob, tab);

    gemm_bt<1, 128, 128><<<768, 256, 0, stream>>>(
        xb, Wqb, Wkb, Wvb, nullptr, Qh, Kh, Vt, tab, NB * SEQ, D_MODEL);

    attn_kernel<<<1024, 256, 0, stream>>>(Qh, Kh, Vt, attn, paO, paM, pbO, pbM);
    attn_merge<<<512, 256, 0, stream>>>(paO, paM, pbO, pbM, attn);

    gemm_bt<0, 64, 128><<<512, 256, 0, stream>>>(
        attn, Wob, Wob, Wob, out, nullptr, nullptr, nullptr, nullptr, NB * SEQ, D_MODEL);
}

// Round 16
// 113.591 us; speedup vs baseline: 1.1141x; 1.0316x over previous
//
#include <hip/hip_runtime.h>

typedef float f32x4 __attribute__((ext_vector_type(4)));
typedef __bf16 bf16x8 __attribute__((ext_vector_type(8)));

#define D_MODEL 1024
#define SEQ     2048
#define NB      2
#define NH      16
#define DK      64

__device__ __forceinline__ unsigned short f2bf(float f) {
    union { float f; unsigned int u; } un; un.f = f;
    unsigned int r = un.u + 0x7fffu + ((un.u >> 16) & 1u);
    return (unsigned short)(r >> 16);
}

__device__ __forceinline__ unsigned cvtpk(float lo, float hi) {
    unsigned r;
    asm("v_cvt_pk_bf16_f32 %0, %1, %2" : "=v"(r) : "v"(lo), "v"(hi));
    return r;
}

__device__ __forceinline__ void gload16(const void* g, void* l) {
    __builtin_amdgcn_global_load_lds((__attribute__((address_space(1))) void*)g,
                                     (__attribute__((address_space(3))) void*)l,
                                     16, 0, 0);
}

// ---------------------------------------------------------------------------
// fused fp32 -> bf16 casts for x and the 4 weights + RoPE cos/sin table
// ---------------------------------------------------------------------------
__global__ __launch_bounds__(256) void cast5(
    const float* __restrict__ x,  const float* __restrict__ wq,
    const float* __restrict__ wk, const float* __restrict__ wv,
    const float* __restrict__ wo,
    unsigned short* __restrict__ xb,  unsigned short* __restrict__ wqb,
    unsigned short* __restrict__ wkb, unsigned short* __restrict__ wvb,
    unsigned short* __restrict__ wob, float2* __restrict__ tab)
{
    if (blockIdx.y == 5) {  // RoPE table: [ss][p] -> (cos, sin), p = d/2 index
        int idx = blockIdx.x * 256 + threadIdx.x;
        if (idx < SEQ * 32) {
            int ss = idx >> 5, p = idx & 31;
            float freq = exp2f(-0.41524101186f * (float)p);  // 10000^(-p/32)
            float sn, cs;
            sincosf((float)ss * freq, &sn, &cs);
            tab[idx] = make_float2(cs, sn);
        }
        return;
    }
    const float* src; unsigned short* dst; int n8;
    switch (blockIdx.y) {
        case 0:  src = x;  dst = xb;  n8 = (NB*SEQ*D_MODEL)/8; break;
        case 1:  src = wq; dst = wqb; n8 = (D_MODEL*D_MODEL)/8; break;
        case 2:  src = wk; dst = wkb; n8 = (D_MODEL*D_MODEL)/8; break;
        case 3:  src = wv; dst = wvb; n8 = (D_MODEL*D_MODEL)/8; break;
        default: src = wo; dst = wob; n8 = (D_MODEL*D_MODEL)/8; break;
    }
    int stride = gridDim.x * blockDim.x;
    for (int i = blockIdx.x * blockDim.x + threadIdx.x; i < n8; i += stride) {
        const float4* p = (const float4*)src + (size_t)i * 2;
        float4 a = p[0], b = p[1];
        union { unsigned short h[8]; uint4 v; } u;
        u.h[0] = f2bf(a.x); u.h[1] = f2bf(a.y); u.h[2] = f2bf(a.z); u.h[3] = f2bf(a.w);
        u.h[4] = f2bf(b.x); u.h[5] = f2bf(b.y); u.h[6] = f2bf(b.z); u.h[7] = f2bf(b.w);
        ((uint4*)dst)[i] = u.v;
    }
}

// ---------------------------------------------------------------------------
// QKV GEMM, 8-wave version (R16): 512 threads, waves 2M x 4N (WM=64, WN=32),
// 128x128 tile, BK=32, triple-buffer + 2-ahead prefetch + counted vmcnt(2),
// rotated conflict-free LDS layout, A-panel XCD clustering. 3 blocks/CU =
// 24 waves/CU (2x the 4-wave version's TLP; R15: MfmaUtil 18.7% at 3 w/SIMD).
// RoPE epilogue per-wave via aliased LDS (Ct 2560 shorts/wave).
// ---------------------------------------------------------------------------
__global__ __launch_bounds__(512, 6) void gemm_qkv8(
    const unsigned short* __restrict__ A,
    const unsigned short* __restrict__ B0,
    const unsigned short* __restrict__ B1,
    const unsigned short* __restrict__ B2,
    unsigned short* __restrict__ Qh,
    unsigned short* __restrict__ Kh,
    unsigned short* __restrict__ Vt,
    const float2* __restrict__ tab,
    int K)
{
    __shared__ __align__(16) unsigned short SM[3 * 256 * 32];  // 48 KB

    const int lane = threadIdx.x & 63;
    const int wid  = threadIdx.x >> 6;           // 0..7
    const int l15 = lane & 15, lhi = lane >> 4;

    // L = (y&7) + 8*(bx + 8*((y>>3) + 4*z))  -> A-panel XCD clustering
    const int L  = blockIdx.x;
    const int yl = L & 7;
    const int t  = L >> 3;
    const int bx = t & 7;
    const int t2 = t >> 3;
    const int y  = ((t2 & 3) << 3) | yl;
    const int z  = t2 >> 2;
    const int m0 = y * 128;
    const int n0 = bx * 128;
    const unsigned short* B = (z == 0) ? B0 : (z == 1) ? B1 : B2;
    const int waveM = (wid >> 2) * 64;           // 0 or 64
    const int waveN = (wid & 3) * 32;            // 0,32,64,96

    f32x4 acc[4][2];
    f32x4 zero = {0.f, 0.f, 0.f, 0.f};
#pragma unroll
    for (int m = 0; m < 4; ++m)
#pragma unroll
        for (int n = 0; n < 2; ++n) acc[m][n] = zero;

    const int lrow = lane >> 2;       // 0..15 row within wave's 16-row chunk
    const int uslot = lane & 3;       // dest 16B slot within row

    // per wave: 1 gload for A (16 rows) + 1 for B (16 rows) = 2 instrs/stage
    auto STAGE = [&](int buf, int k0) {
        unsigned short* as = SM + buf * 256 * 32;
        unsigned short* bs = as + 128 * 32;
        int rbase = wid * 16;
        int r = rbase + lrow;
        int ug = (uslot - (r >> 1)) & 3;     // rotated global source unit
        gload16(A + (size_t)(m0 + r) * K + k0 + ug * 8, (char*)as + rbase * 64);
        gload16(B + (size_t)(n0 + r) * K + k0 + ug * 8, (char*)bs + rbase * 64);
    };

    const int NK = K >> 5;            // 32 K-steps
    STAGE(0, 0);
    STAGE(1, 32);

    for (int k = 0; k < NK; ++k) {
        if (k < NK - 1) asm volatile("s_waitcnt vmcnt(2)" ::: "memory");
        else            asm volatile("s_waitcnt vmcnt(0)" ::: "memory");
        __builtin_amdgcn_s_barrier();
        __builtin_amdgcn_sched_barrier(0);
        if (k + 2 < NK) STAGE((k + 2) % 3, (k + 2) << 5);

        const unsigned short* as = SM + (k % 3) * 256 * 32;
        const unsigned short* bs = as + 128 * 32;
        bf16x8 af[4], bfr[2];
#pragma unroll
        for (int m = 0; m < 4; ++m) {
            int ra = waveM + m * 16 + l15;
            af[m] = *(const bf16x8*)(as + ra * 32 + (((lhi + (ra >> 1)) & 3) << 3));
        }
#pragma unroll
        for (int n = 0; n < 2; ++n) {
            int rb = waveN + n * 16 + l15;
            bfr[n] = *(const bf16x8*)(bs + rb * 32 + (((lhi + (rb >> 1)) & 3) << 3));
        }
        __builtin_amdgcn_s_setprio(1);
#pragma unroll
        for (int m = 0; m < 4; ++m)
#pragma unroll
            for (int n = 0; n < 2; ++n)
                acc[m][n] = __builtin_amdgcn_mfma_f32_16x16x32_bf16(af[m], bfr[n], acc[m][n], 0, 0, 0);
        __builtin_amdgcn_s_setprio(0);
    }

    __syncthreads();  // all waves done with stage buffers before aliasing
    unsigned short* Ct = ((unsigned short*)SM) + wid * 2560;  // per-wave
    const int colg0 = n0 + waveN;             // 32-aligned within a head
    const int hh    = colg0 >> 6;
    const int dd0   = colg0 & 63;             // 0 or 32
    const int rowg0 = m0 + waveM;             // 64-aligned
    const int bb    = rowg0 >> 11;
    const int ss0   = rowg0 & (SEQ - 1);
    const size_t bhh = (size_t)(bb * NH + hh);

    // phase 1: RoPE + pack into LDS (Q/K: [rl][cl] 40-stride; V: [cl][rl] 72)
#pragma unroll
    for (int n = 0; n < 2; ++n) {
        int cl = n * 16 + l15;                // 0..31, dd = dd0 + cl
#pragma unroll
        for (int m = 0; m < 4; ++m) {
#pragma unroll
            for (int r = 0; r < 4; ++r) {
                float v  = acc[m][n][r];
                float pv = __shfl_xor(v, 1);  // RoPE pair partner (dd^1)
                int rl = m * 16 + (lhi << 2) + r;   // local row 0..63
                if (z == 2) {
                    Ct[cl * 72 + rl] = f2bf(v);
                } else {
                    int ss = (rowg0 + rl) & (SEQ - 1);
                    int dd = dd0 + cl;
                    float2 cs = tab[(ss << 5) + (dd >> 1)];
                    float o = (dd & 1) ? (pv * cs.y + v * cs.x)
                                       : (v * cs.x - pv * cs.y);
                    if (z == 0) o *= 0.18033688011f;  // (1/8)*log2(e)
                    Ct[rl * 40 + cl] = f2bf(o);
                }
            }
        }
    }
    asm volatile("s_waitcnt lgkmcnt(0)" ::: "memory");

    if (z == 2) {
        // V: 32 dd-rows x 64 ss (128 B per row), 4 iters x (8 dd x 8 chunks)
        const int ddl0 = lane >> 3;           // 0..7
        const int sc   = (lane & 7) << 3;     // ss chunk 0..56
#pragma unroll
        for (int i = 0; i < 4; ++i) {
            int ddl = i * 8 + ddl0;
            uint4 w = *(const uint4*)&Ct[ddl * 72 + sc];
            *(uint4*)(Vt + (bhh * DK + dd0 + ddl) * SEQ + ss0 + sc) = w;
        }
    } else {
        // Q/K: 64 rows x 32 dd (64 B per row), 4 iters x (16 rows x 4 chunks)
        const int rl0 = lane >> 2;            // 0..15
        const int cc  = (lane & 3) << 3;      // col chunk 0..24
        unsigned short* dst = (z == 0) ? Qh : Kh;
#pragma unroll
        for (int i = 0; i < 4; ++i) {
            int rl = i * 16 + rl0;
            uint4 w = *(const uint4*)&Ct[rl * 40 + cc];
            int ss = (rowg0 + rl) & (SEQ - 1);
            *(uint4*)(dst + (bhh * SEQ + ss) * DK + dd0 + cc) = w;
        }
    }
}

// ---------------------------------------------------------------------------
// GEMM MODE 0 (final projection, unchanged from R15): 4 waves, BM=64 BN=128,
// triple-buffer + 2-ahead + vmcnt(3), rotation, XCD clustering.
// ---------------------------------------------------------------------------
__global__ __launch_bounds__(256) void gemm_out(
    const unsigned short* __restrict__ A,
    const unsigned short* __restrict__ B0,
    float* __restrict__ outF,
    int M, int K)
{
    constexpr int BM = 64, BN = 128;
    __shared__ __align__(16) unsigned short SM[3 * (BM + BN) * 32];

    const int lane = threadIdx.x & 63;
    const int wid  = threadIdx.x >> 6;
    const int l15 = lane & 15, lhi = lane >> 4;

    const int L  = blockIdx.x;
    const int yl = L & 7;
    const int t  = L >> 3;
    const int bx = t & 7;
    const int t2 = t >> 3;
    const int y  = (t2 << 3) | yl;
    const int m0 = y * BM;
    const int n0 = bx * BN;
    const unsigned short* B = B0;
    const int waveM = (wid >> 1) * 32;
    const int waveN = (wid & 1) * 64;

    f32x4 acc[2][4];
    f32x4 zero = {0.f, 0.f, 0.f, 0.f};
#pragma unroll
    for (int m = 0; m < 2; ++m)
#pragma unroll
        for (int n = 0; n < 4; ++n) acc[m][n] = zero;

    const int lrow = lane >> 2;
    const int uslot = lane & 3;

    auto STAGE = [&](int buf, int k0) {
        unsigned short* as = SM + buf * (BM + BN) * 32;
        unsigned short* bs = as + BM * 32;
        {
            int rbase = wid * 16;
            int r = rbase + lrow;
            int ug = (uslot - (r >> 1)) & 3;
            gload16(A + (size_t)(m0 + r) * K + k0 + ug * 8,
                    (char*)as + rbase * 64);
        }
#pragma unroll
        for (int q = 0; q < 2; ++q) {
            int rbase = wid * 32 + q * 16;
            int r = rbase + lrow;
            int ug = (uslot - (r >> 1)) & 3;
            gload16(B + (size_t)(n0 + r) * K + k0 + ug * 8,
                    (char*)bs + rbase * 64);
        }
    };

    const int NK = K >> 5;
    STAGE(0, 0);
    STAGE(1, 32);

    for (int k = 0; k < NK; ++k) {
        if (k < NK - 1) asm volatile("s_waitcnt vmcnt(3)" ::: "memory");
        else            asm volatile("s_waitcnt vmcnt(0)" ::: "memory");
        __builtin_amdgcn_s_barrier();
        __builtin_amdgcn_sched_barrier(0);
        if (k + 2 < NK) STAGE((k + 2) % 3, (k + 2) << 5);

        const unsigned short* as = SM + (k % 3) * (BM + BN) * 32;
        const unsigned short* bs = as + BM * 32;
        bf16x8 af[2], bfr[4];
#pragma unroll
        for (int m = 0; m < 2; ++m) {
            int ra = waveM + m * 16 + l15;
            af[m] = *(const bf16x8*)(as + ra * 32 + (((lhi + (ra >> 1)) & 3) << 3));
        }
#pragma unroll
        for (int n = 0; n < 4; ++n) {
            int rb = waveN + n * 16 + l15;
            bfr[n] = *(const bf16x8*)(bs + rb * 32 + (((lhi + (rb >> 1)) & 3) << 3));
        }
        __builtin_amdgcn_s_setprio(1);
#pragma unroll
        for (int m = 0; m < 2; ++m)
#pragma unroll
            for (int n = 0; n < 4; ++n)
                acc[m][n] = __builtin_amdgcn_mfma_f32_16x16x32_bf16(af[m], bfr[n], acc[m][n], 0, 0, 0);
        __builtin_amdgcn_s_setprio(0);
    }

#pragma unroll
    for (int n = 0; n < 4; ++n) {
        int col = n0 + waveN + n * 16 + l15;
#pragma unroll
        for (int m = 0; m < 2; ++m) {
            int rowb = m0 + waveM + m * 16 + (lhi << 2);
#pragma unroll
            for (int r = 0; r < 4; ++r)
                outF[(size_t)(rowb + r) * D_MODEL + col] = acc[m][n][r];
        }
    }
}

// ---------------------------------------------------------------------------
// causal flash attention v12 (R15, unchanged): SPLIT-K, 1024 uniform blocks,
// kv-64, 2-buf gload_lds, both-sides XOR swizzle, cvt_pk P-LDS, defer-max.
// ---------------------------------------------------------------------------
__global__ __launch_bounds__(256) void attn_kernel(
    const unsigned short* __restrict__ Qh,
    const unsigned short* __restrict__ Kh,
    const unsigned short* __restrict__ Vt,
    unsigned short* __restrict__ O,
    float* __restrict__ paO, float2* __restrict__ paM,
    float* __restrict__ pbO, float2* __restrict__ pbM)
{
    __shared__ unsigned short Ks[2][64 * 64];
    __shared__ unsigned short Vs[2][64 * 64];
    __shared__ unsigned short P[4][16 * 64];

    const int tid  = threadIdx.x;
    const int lane = tid & 63;
    const int wid  = tid >> 6;
    const int l15 = lane & 15, lhi = lane >> 4;

    const int L    = blockIdx.x;
    const int xcd  = L & 7;
    const int r0   = L >> 3;
    const int bh   = (xcd << 2) | (r0 & 3);
    const int rest = r0 >> 2;
    const int pi   = rest & 15;
    const int j    = rest >> 4;
    const int b = bh >> 4, h = bh & 15;
    const size_t p = (size_t)bh * 16 + (15 - pi);

    const unsigned short* Qb = Qh + (size_t)bh * SEQ * DK;
    const unsigned short* Kb = Kh + (size_t)bh * SEQ * DK;
    const unsigned short* Vb = Vt + (size_t)bh * DK * SEQ;

    const int NT = j ? 16 : 17;

    auto kv_of = [&](int g) {
        if (j) return 16 - pi + g;
        return (g <= pi) ? g : g - (pi + 1);
    };

    auto STAGE = [&](int buf, int kvt) {
        int kv0s = kvt << 6;
#pragma unroll
        for (int c = 0; c < 2; ++c) {
            int ub = c * 256 + wid * 64;
            int u  = ub + lane;
            int kr = u >> 3;
            int kc = (u & 7) ^ (kr & 7);
            gload16(Kb + (size_t)(kv0s + kr) * DK + kc * 8, &Ks[buf][(size_t)ub * 8]);
            gload16(Vb + (size_t)kr * SEQ + kv0s + kc * 8, &Vs[buf][(size_t)ub * 8]);
        }
    };

    const f32x4 zero = {0.f, 0.f, 0.f, 0.f};
    const f32x4 ninf = {-1e30f, -1e30f, -1e30f, -1e30f};
    const int sw = l15 & 7;

    STAGE(0, kv_of(0));
    int g = 0;

    const int nph = j ? 1 : 2;
    for (int ph = 0; ph < nph; ++ph) {
        int qt, ktbeg, ktend, dodiag, finalw;
        if (j == 0 && ph == 0) { qt = pi;      ktbeg = 0;       ktend = pi;      dodiag = 1; finalw = 1; }
        else if (j == 0)       { qt = 31 - pi; ktbeg = 0;       ktend = 15 - pi; dodiag = 0; finalw = 0; }
        else                   { qt = 31 - pi; ktbeg = 16 - pi; ktend = 31 - pi; dodiag = 1; finalw = 0; }

        const int q0 = qt << 6;
        const int qw = q0 + wid * 16;

        bf16x8 qf[2];
#pragma unroll
        for (int kk = 0; kk < 2; ++kk)
            qf[kk] = *(const bf16x8*)(Qb + (size_t)(qw + l15) * DK + kk * 32 + lhi * 8);

        f32x4 oacc[4];
#pragma unroll
        for (int nd = 0; nd < 4; ++nd) oacc[nd] = zero;
        float mrow = -1e30f;
        float lrow = 0.f;

        for (int kt = ktbeg; kt <= ktend; ++kt, ++g) {
            const int kv0 = kt << 6;
            const bool diag = dodiag && (kt == ktend);
            const int nlim = diag ? (wid + 1) : 4;

            asm volatile("s_waitcnt vmcnt(0)" ::: "memory");
            __builtin_amdgcn_s_barrier();
            __builtin_amdgcn_sched_barrier(0);
            if (g + 1 < NT) STAGE((g + 1) & 1, kv_of(g + 1));

            const unsigned short* Kc = Ks[g & 1];
            const unsigned short* Vc = Vs[g & 1];

            f32x4 s[4];
#pragma unroll
            for (int n = 0; n < 4; ++n) s[n] = (n < nlim) ? zero : ninf;

            __builtin_amdgcn_s_setprio(1);
#pragma unroll
            for (int n = 0; n < 4; ++n) {
                if (n < nlim) {
                    int rr = n * 16 + l15;
                    bf16x8 k0 = *(const bf16x8*)&Kc[rr * 64 + ((lhi ^ sw) << 3)];
                    bf16x8 k1 = *(const bf16x8*)&Kc[rr * 64 + (((4 + lhi) ^ sw) << 3)];
                    s[n] = __builtin_amdgcn_mfma_f32_16x16x32_bf16(k0, qf[0], s[n], 0, 0, 0);
                    s[n] = __builtin_amdgcn_mfma_f32_16x16x32_bf16(k1, qf[1], s[n], 0, 0, 0);
                }
            }
            __builtin_amdgcn_s_setprio(0);

            if (diag) {
                const int qg = qw + l15;
#pragma unroll
                for (int n = 0; n < 4; ++n) {
                    if (n < nlim) {
#pragma unroll
                        for (int rr = 0; rr < 4; ++rr) {
                            int kg = kv0 + n * 16 + (lhi << 2) + rr;
                            if (kg > qg) s[n][rr] = -1e30f;
                        }
                    }
                }
            }

            float mx = fmaxf(fmaxf(s[0][0], s[0][1]), fmaxf(s[0][2], s[0][3]));
#pragma unroll
            for (int n = 1; n < 4; ++n)
                mx = fmaxf(mx, fmaxf(fmaxf(s[n][0], s[n][1]), fmaxf(s[n][2], s[n][3])));
            mx = fmaxf(mx, __shfl_xor(mx, 16));
            mx = fmaxf(mx, __shfl_xor(mx, 32));

            float alpha = 1.f;
            const int allDefer = __all(mx <= mrow + 8.f);
            if (!allDefer) {
                float mn = fmaxf(mrow, mx);
                alpha = __builtin_amdgcn_exp2f(mrow - mn);
                mrow = mn;
            }

#pragma unroll
            for (int n = 0; n < 4; ++n)
#pragma unroll
                for (int rr = 0; rr < 4; ++rr)
                    s[n][rr] = __builtin_amdgcn_exp2f(s[n][rr] - mrow);

            float rs = 0.f;
#pragma unroll
            for (int n = 0; n < 4; ++n)
                rs += (s[n][0] + s[n][1]) + (s[n][2] + s[n][3]);
            rs += __shfl_xor(rs, 16);
            rs += __shfl_xor(rs, 32);
            lrow = allDefer ? (lrow + rs) : (lrow * alpha + rs);

#pragma unroll
            for (int n = 0; n < 4; ++n) {
                uint2 pk;
                pk.x = cvtpk(s[n][0], s[n][1]);
                pk.y = cvtpk(s[n][2], s[n][3]);
                int cW = 2 * n + (lhi >> 1);
                *(uint2*)&P[wid][(l15 << 6) + ((cW ^ sw) << 3) + ((lhi & 1) << 2)] = pk;
            }

            if (!allDefer) {
                float a0 = __shfl(alpha, (lhi << 2) + 0);
                float a1 = __shfl(alpha, (lhi << 2) + 1);
                float a2 = __shfl(alpha, (lhi << 2) + 2);
                float a3 = __shfl(alpha, (lhi << 2) + 3);
#pragma unroll
                for (int nd = 0; nd < 4; ++nd) {
                    oacc[nd][0] *= a0; oacc[nd][1] *= a1;
                    oacc[nd][2] *= a2; oacc[nd][3] *= a3;
                }
            }

            asm volatile("s_waitcnt lgkmcnt(0)" ::: "memory");
            const int kklim = diag ? ((nlim + 1) >> 1) : 2;
            bf16x8 pa[2];
#pragma unroll
            for (int kk = 0; kk < 2; ++kk)
                if (kk < kklim)
                    pa[kk] = *(const bf16x8*)&P[wid][(l15 << 6) + ((((kk << 2) + lhi) ^ sw) << 3)];

            __builtin_amdgcn_s_setprio(1);
#pragma unroll
            for (int nd = 0; nd < 4; ++nd)
#pragma unroll
                for (int kk = 0; kk < 2; ++kk)
                    if (kk < kklim) {
                        int rd = nd * 16 + l15;
                        bf16x8 vf = *(const bf16x8*)&Vc[rd * 64 + ((((kk << 2) + lhi) ^ sw) << 3)];
                        oacc[nd] = __builtin_amdgcn_mfma_f32_16x16x32_bf16(pa[kk], vf, oacc[nd], 0, 0, 0);
                    }
            __builtin_amdgcn_s_setprio(0);
        }

        if (finalw) {
            float inv = 1.f / lrow;
            float i0 = __shfl(inv, (lhi << 2) + 0);
            float i1 = __shfl(inv, (lhi << 2) + 1);
            float i2 = __shfl(inv, (lhi << 2) + 2);
            float i3 = __shfl(inv, (lhi << 2) + 3);
#pragma unroll
            for (int nd = 0; nd < 4; ++nd) {
                int d = nd * 16 + l15;
                int rowb = qw + (lhi << 2);
                O[((size_t)(b * SEQ + rowb + 0)) * D_MODEL + h * DK + d] = f2bf(oacc[nd][0] * i0);
                O[((size_t)(b * SEQ + rowb + 1)) * D_MODEL + h * DK + d] = f2bf(oacc[nd][1] * i1);
                O[((size_t)(b * SEQ + rowb + 2)) * D_MODEL + h * DK + d] = f2bf(oacc[nd][2] * i2);
                O[((size_t)(b * SEQ + rowb + 3)) * D_MODEL + h * DK + d] = f2bf(oacc[nd][3] * i3);
            }
        } else {
            float*  PO = (j ? pbO : paO) + p * 4096;
            float2* PM = (j ? pbM : paM) + p * 64;
#pragma unroll
            for (int nd = 0; nd < 4; ++nd)
#pragma unroll
                for (int rr = 0; rr < 4; ++rr) {
                    int rowl = wid * 16 + (lhi << 2) + rr;
                    PO[rowl * 64 + nd * 16 + l15] = oacc[nd][rr];
                }
            if (lhi == 0)
                PM[wid * 16 + l15] = make_float2(mrow, lrow);
        }
    }
}

// ---------------------------------------------------------------------------
// merge two partials per split q-tile via online-softmax algebra
// ---------------------------------------------------------------------------
__global__ __launch_bounds__(256) void attn_merge(
    const float* __restrict__ paO, const float2* __restrict__ paM,
    const float* __restrict__ pbO, const float2* __restrict__ pbM,
    unsigned short* __restrict__ O)
{
    const int mb = blockIdx.x;
    const int bh = mb >> 4, qq = mb & 15;
    const int b = bh >> 4, h = bh & 15;
    const int q0 = (16 + qq) << 6;
    const size_t p = (size_t)bh * 16 + qq;
    const int t = threadIdx.x;
    const int r = t >> 2;
    const int c0 = (t & 3) << 4;

    float2 ma = paM[p * 64 + r];
    float2 mbv = pbM[p * 64 + r];
    float m = fmaxf(ma.x, mbv.x);
    float a1 = __builtin_amdgcn_exp2f(ma.x - m);
    float a2 = __builtin_amdgcn_exp2f(mbv.x - m);
    float inv = 1.f / (ma.y * a1 + mbv.y * a2);

    const float* o1 = paO + p * 4096 + r * 64 + c0;
    const float* o2 = pbO + p * 4096 + r * 64 + c0;
    union { unsigned short hh[16]; uint4 v[2]; } u;
#pragma unroll
    for (int c = 0; c < 16; ++c)
        u.hh[c] = f2bf((o1[c] * a1 + o2[c] * a2) * inv);
    uint4* dst = (uint4*)(O + ((size_t)(b * SEQ + q0 + r)) * D_MODEL + h * DK + c0);
    dst[0] = u.v[0];
    dst[1] = u.v[1];
}

// ---------------------------------------------------------------------------
extern "C" void kernel_launch(void* const* d_in, const int* in_sizes, int n_in,
                              void* d_out, int out_size, void* d_ws, size_t ws_size,
                              hipStream_t stream)
{
    const float* x  = (const float*)d_in[0];
    const float* Wq = (const float*)d_in[1];
    const float* Wk = (const float*)d_in[2];
    const float* Wv = (const float*)d_in[3];
    const float* Wo = (const float*)d_in[4];
    float* out = (float*)d_out;

    char* ws = (char*)d_ws;
    unsigned short* xb  = (unsigned short*)(ws);                    // 8 MB (reused as attn buf)
    unsigned short* Wqb = (unsigned short*)(ws + ( 8ull << 20));
    unsigned short* Wkb = (unsigned short*)(ws + (10ull << 20));
    unsigned short* Wvb = (unsigned short*)(ws + (12ull << 20));
    unsigned short* Wob = (unsigned short*)(ws + (14ull << 20));
    unsigned short* Qh  = (unsigned short*)(ws + (16ull << 20));    // [bh][s][64]
    unsigned short* Kh  = (unsigned short*)(ws + (24ull << 20));    // [bh][s][64]
    unsigned short* Vt  = (unsigned short*)(ws + (32ull << 20));    // [bh][64][s]
    float2*         tab = (float2*)(ws + (40ull << 20));            // 512 KB RoPE table
    unsigned short* attn = xb;

    float*  paO = out;                                   // 8 MB (scratch until gemm_out)
    float2* paM = (float2*)(out + 512 * 4096);           // 256 KB
    float*  pbO = (float*)(ws + (41ull << 20));          // 8 MB
    float2* pbM = (float2*)(ws + (49ull << 20));         // 256 KB

    cast5<<<dim3(512, 6), 256, 0, stream>>>(x, Wq, Wk, Wv, Wo, xb, Wqb, Wkb, Wvb, Wob, tab);

    gemm_qkv8<<<768, 512, 0, stream>>>(
        xb, Wqb, Wkb, Wvb, Qh, Kh, Vt, tab, D_MODEL);

    attn_kernel<<<1024, 256, 0, stream>>>(Qh, Kh, Vt, attn, paO, paM, pbO, pbM);
    attn_merge<<<512, 256, 0, stream>>>(paO, paM, pbO, pbM, attn);

    gemm_out<<<512, 256, 0, stream>>>(attn, Wob, out, NB * SEQ, D_MODEL);
}